// Round 8
// baseline (446.854 us; speedup 1.0000x reference)
//
#include <hip/hip_runtime.h>
#include <hip/hip_cooperative_groups.h>

namespace cg = cooperative_groups;

// GraphSAGE (2x SAGEConv mean + global_mean_pool + linear) collapsed algebraically:
// out = (((St@W1l + Sw@W1r + Wsum*b1) @ W2l + (Sw@W1l + Sx@W1r + N*b1) @ W2r)/N + b2) @ Wout + bout
// invc_i = 1/max(indeg_i,1), ws_j = sum_{e:src=j} invc[dst_e], u_j = ws_j*invc_j,
// t_k = sum_{e:src=k} u[dst_e]; Sx/Sw/St = weighted column sums of x; Wsum = sum ws.
//
// R7: whole pipeline in ONE cooperative kernel, 256 blocks x 1024 thr
// (1 block/CU, all co-resident), grid.sync() between phases. Edge scatters:
// LDS range privatization NR=16 x RS=6250 (25 KB), NC=16 chunks; partial
// 6.4 MB (R6's NC=64 grew it 4x — flush/merge HBM traffic beat the L2-cheap
// redundant edge reads it saved). bid = r*16+c => chunk siblings share
// bid mod 16 => same XCD under round-robin dispatch => L2-local re-reads.

#define NN    100000
#define NE    1600000
#define FEAT  128
#define NCLS  40
#define NR    16
#define RS    6250     // NN / NR
#define NC    16
#define PER   25000    // (NE/4)/NC int4s per chunk
#define GRID  256      // NR*NC
#define BLK   1024

struct FS {
    float shx[32][32][4];
    float shw[32][32][4];
    float sht[32][32][4];
    float wsum[32];
};
union SH {
    unsigned ctab[RS];
    float    ftab[RS];
    FS       fs;
    float    fin[800];
};

__global__ __launch_bounds__(BLK, 4) void k_all(
        const float* __restrict__ x,
        const int4* __restrict__ src4, const int4* __restrict__ dst4,
        const float* __restrict__ W1l, const float* __restrict__ W1r, const float* __restrict__ b1,
        const float* __restrict__ W2l, const float* __restrict__ W2r, const float* __restrict__ b2,
        const float* __restrict__ Wout, const float* __restrict__ bout,
        float* __restrict__ out,
        float* __restrict__ partial, float* __restrict__ invc,
        float* __restrict__ ws, float* __restrict__ u, float* __restrict__ t,
        float* __restrict__ fsbuf) {
    cg::grid_group grid = cg::this_grid();
    __shared__ SH sh;

    const int bid = blockIdx.x;
    const int tid = threadIdx.x;
    const int c = bid & (NC - 1);
    const int r = bid >> 4;
    const int base = r * RS;
    const int i0 = c * PER;

    // ---------------- phase 1: in-degree count ----------------
    for (int j = tid; j < RS; j += BLK) sh.ctab[j] = 0u;
    __syncthreads();
    for (int i = i0 + tid; i < i0 + PER; i += BLK) {
        int4 d = dst4[i];
        unsigned a;
        a = (unsigned)(d.x - base); if (a < RS) atomicAdd(&sh.ctab[a], 1u);
        a = (unsigned)(d.y - base); if (a < RS) atomicAdd(&sh.ctab[a], 1u);
        a = (unsigned)(d.z - base); if (a < RS) atomicAdd(&sh.ctab[a], 1u);
        a = (unsigned)(d.w - base); if (a < RS) atomicAdd(&sh.ctab[a], 1u);
    }
    __syncthreads();
    {
        unsigned* outp = (unsigned*)partial + (size_t)(r * NC + c) * RS;
        for (int j = tid; j < RS; j += BLK) outp[j] = sh.ctab[j];
    }
    grid.sync();

    // ---------------- phase 2: merge -> invc ----------------
    {
        int i = bid * BLK + tid;               // 262144 threads >= NN
        if (i < NN) {
            int rr = i / RS, jj = i - rr * RS;
            const unsigned* p = (const unsigned*)partial + (size_t)rr * NC * RS + jj;
            unsigned cn = 0;
            #pragma unroll
            for (int cc = 0; cc < NC; ++cc) cn += p[(size_t)cc * RS];
            invc[i] = 1.0f / (float)(cn > 0u ? cn : 1u);
        }
    }
    grid.sync();

    // ---------------- phase 3: ws scatter (val = invc) ----------------
    for (int j = tid; j < RS; j += BLK) sh.ftab[j] = 0.f;
    __syncthreads();
    for (int i = i0 + tid; i < i0 + PER; i += BLK) {
        int4 s = src4[i];
        int4 d = dst4[i];
        unsigned a;
        a = (unsigned)(s.x - base); if (a < RS) atomicAdd(&sh.ftab[a], invc[d.x]);
        a = (unsigned)(s.y - base); if (a < RS) atomicAdd(&sh.ftab[a], invc[d.y]);
        a = (unsigned)(s.z - base); if (a < RS) atomicAdd(&sh.ftab[a], invc[d.z]);
        a = (unsigned)(s.w - base); if (a < RS) atomicAdd(&sh.ftab[a], invc[d.w]);
    }
    __syncthreads();
    {
        float* outp = partial + (size_t)(r * NC + c) * RS;
        for (int j = tid; j < RS; j += BLK) outp[j] = sh.ftab[j];
    }
    grid.sync();

    // ---------------- phase 4: merge -> ws, u ----------------
    {
        int i = bid * BLK + tid;
        if (i < NN) {
            int rr = i / RS, jj = i - rr * RS;
            const float* p = partial + (size_t)rr * NC * RS + jj;
            float w = 0.f;
            #pragma unroll
            for (int cc = 0; cc < NC; ++cc) w += p[(size_t)cc * RS];
            ws[i] = w;
            u[i] = w * invc[i];
        }
    }
    grid.sync();

    // ---------------- phase 5: t scatter (val = u) ----------------
    for (int j = tid; j < RS; j += BLK) sh.ftab[j] = 0.f;
    __syncthreads();
    for (int i = i0 + tid; i < i0 + PER; i += BLK) {
        int4 s = src4[i];
        int4 d = dst4[i];
        unsigned a;
        a = (unsigned)(s.x - base); if (a < RS) atomicAdd(&sh.ftab[a], u[d.x]);
        a = (unsigned)(s.y - base); if (a < RS) atomicAdd(&sh.ftab[a], u[d.y]);
        a = (unsigned)(s.z - base); if (a < RS) atomicAdd(&sh.ftab[a], u[d.z]);
        a = (unsigned)(s.w - base); if (a < RS) atomicAdd(&sh.ftab[a], u[d.w]);
    }
    __syncthreads();
    {
        float* outp = partial + (size_t)(r * NC + c) * RS;
        for (int j = tid; j < RS; j += BLK) outp[j] = sh.ftab[j];
    }
    grid.sync();

    // ---------------- phase 6: merge -> t ----------------
    {
        int i = bid * BLK + tid;
        if (i < NN) {
            int rr = i / RS, jj = i - rr * RS;
            const float* p = partial + (size_t)rr * NC * RS + jj;
            float v = 0.f;
            #pragma unroll
            for (int cc = 0; cc < NC; ++cc) v += p[(size_t)cc * RS];
            t[i] = v;
        }
    }
    grid.sync();

    // ---------------- phase 7: feature sums (x sweep) ----------------
    {
        const int lane = tid & 31;
        const int grp  = tid >> 5;            // 0..31
        float sx0=0,sx1=0,sx2=0,sx3=0;
        float sw0=0,sw1=0,sw2=0,sw3=0;
        float st0=0,st1=0,st2=0,st3=0;
        float wsum = 0.f;
        for (int row = bid * 32 + grp; row < NN; row += GRID * 32) {
            const float4* xr = (const float4*)(x + (size_t)row * FEAT);
            float4 v = xr[lane];
            float wr = ws[row];
            float tr = t[row];
            sx0 += v.x; sx1 += v.y; sx2 += v.z; sx3 += v.w;
            sw0 += wr*v.x; sw1 += wr*v.y; sw2 += wr*v.z; sw3 += wr*v.w;
            st0 += tr*v.x; st1 += tr*v.y; st2 += tr*v.z; st3 += tr*v.w;
            if (lane == 0) wsum += wr;
        }
        __syncthreads();   // sh.ftab (phase 5) no longer needed; switch to sh.fs
        sh.fs.shx[grp][lane][0]=sx0; sh.fs.shx[grp][lane][1]=sx1;
        sh.fs.shx[grp][lane][2]=sx2; sh.fs.shx[grp][lane][3]=sx3;
        sh.fs.shw[grp][lane][0]=sw0; sh.fs.shw[grp][lane][1]=sw1;
        sh.fs.shw[grp][lane][2]=sw2; sh.fs.shw[grp][lane][3]=sw3;
        sh.fs.sht[grp][lane][0]=st0; sh.fs.sht[grp][lane][1]=st1;
        sh.fs.sht[grp][lane][2]=st2; sh.fs.sht[grp][lane][3]=st3;
        if (lane == 0) sh.fs.wsum[grp] = wsum;
        __syncthreads();
        if (grp == 0) {
            float ax[4]={0,0,0,0}, aw[4]={0,0,0,0}, at[4]={0,0,0,0};
            for (int g = 0; g < 32; ++g) {
                #pragma unroll
                for (int cc = 0; cc < 4; ++cc) {
                    ax[cc] += sh.fs.shx[g][lane][cc];
                    aw[cc] += sh.fs.shw[g][lane][cc];
                    at[cc] += sh.fs.sht[g][lane][cc];
                }
            }
            #pragma unroll
            for (int cc = 0; cc < 4; ++cc) {
                fsbuf[(size_t)(        4*lane + cc) * GRID + bid] = ax[cc];
                fsbuf[(size_t)(FEAT  + 4*lane + cc) * GRID + bid] = aw[cc];
                fsbuf[(size_t)(2*FEAT+ 4*lane + cc) * GRID + bid] = at[cc];
            }
            if (lane == 0) {
                float w = 0.f;
                for (int g = 0; g < 32; ++g) w += sh.fs.wsum[g];
                fsbuf[(size_t)(3*FEAT) * GRID + bid] = w;
            }
        }
    }
    grid.sync();

    // ---------------- phase 8: final reduce + matvecs (block 0) ----------------
    if (bid != 0) return;
    for (int v = tid; v < 3*FEAT + 1; v += BLK) {
        const float* pp = fsbuf + (size_t)v * GRID;
        float s = 0.f;
        for (int b = 0; b < GRID; ++b) s += pp[b];
        sh.fin[v] = s;      // [0..127]=Sx  [128..255]=Sw  [256..383]=St  [384]=Wsum
    }
    __syncthreads();
    if (tid < FEAT) {
        float m1 = (float)NN * b1[tid];
        float s2 = sh.fin[384] * b1[tid];
        for (int k = 0; k < FEAT; ++k) {
            float wl = W1l[k*FEAT + tid];
            float wr = W1r[k*FEAT + tid];
            m1 += sh.fin[128 + k] * wl + sh.fin[k] * wr;        // Sw@W1l + Sx@W1r
            s2 += sh.fin[256 + k] * wl + sh.fin[128 + k] * wr;  // St@W1l + Sw@W1r
        }
        sh.fin[400 + tid] = m1;
        sh.fin[528 + tid] = s2;
    }
    __syncthreads();
    if (tid < FEAT) {
        float g = 0.f;
        for (int k = 0; k < FEAT; ++k)
            g += sh.fin[528 + k] * W2l[k*FEAT + tid] + sh.fin[400 + k] * W2r[k*FEAT + tid];
        sh.fin[656 + tid] = g * (1.0f / (float)NN) + b2[tid];
    }
    __syncthreads();
    if (tid < NCLS) {
        float o = bout[tid];
        for (int k = 0; k < FEAT; ++k)
            o += sh.fin[656 + k] * Wout[k*NCLS + tid];
        out[tid] = o;
    }
}

// ======================= non-cooperative fallback =======================

__global__ __launch_bounds__(256) void k_count_dev(const int4* __restrict__ dst4, int* __restrict__ cnt) {
    int i = blockIdx.x * 256 + threadIdx.x;
    if (i >= NE / 4) return;
    int4 d = dst4[i];
    atomicAdd(&cnt[d.x], 1); atomicAdd(&cnt[d.y], 1);
    atomicAdd(&cnt[d.z], 1); atomicAdd(&cnt[d.w], 1);
}

__global__ __launch_bounds__(256) void k_inv_dev(const int* __restrict__ cnt, float* __restrict__ invc) {
    int i = blockIdx.x * 256 + threadIdx.x;
    if (i >= NN) return;
    int c = cnt[i];
    invc[i] = 1.0f / (float)(c > 0 ? c : 1);
}

__global__ __launch_bounds__(256) void k_ws_dev(const int4* __restrict__ src4, const int4* __restrict__ dst4,
                                                const float* __restrict__ invc, float* __restrict__ ws) {
    int i = blockIdx.x * 256 + threadIdx.x;
    if (i >= NE / 4) return;
    int4 s = src4[i];
    int4 d = dst4[i];
    atomicAdd(&ws[s.x], invc[d.x]); atomicAdd(&ws[s.y], invc[d.y]);
    atomicAdd(&ws[s.z], invc[d.z]); atomicAdd(&ws[s.w], invc[d.w]);
}

__global__ __launch_bounds__(256) void k_u_dev(const float* __restrict__ ws, const float* __restrict__ invc,
                                               float* __restrict__ u) {
    int i = blockIdx.x * 256 + threadIdx.x;
    if (i >= NN) return;
    u[i] = ws[i] * invc[i];
}

__global__ __launch_bounds__(256) void k_t_dev(const int4* __restrict__ src4, const int4* __restrict__ dst4,
                                               const float* __restrict__ u, float* __restrict__ t) {
    int i = blockIdx.x * 256 + threadIdx.x;
    if (i >= NE / 4) return;
    int4 s = src4[i];
    int4 d = dst4[i];
    atomicAdd(&t[s.x], u[d.x]); atomicAdd(&t[s.y], u[d.y]);
    atomicAdd(&t[s.z], u[d.z]); atomicAdd(&t[s.w], u[d.w]);
}

__global__ __launch_bounds__(256) void k_fs_atom(const float* __restrict__ x,
                                                 const float* __restrict__ ws,
                                                 const float* __restrict__ t,
                                                 float* __restrict__ sums) {
    int lane = threadIdx.x & 31;
    int grp  = threadIdx.x >> 5;
    int row0 = blockIdx.x * 8 + grp;
    int rstride = gridDim.x * 8;
    float sx0=0,sx1=0,sx2=0,sx3=0, sw0=0,sw1=0,sw2=0,sw3=0, st0=0,st1=0,st2=0,st3=0, wsum=0.f;
    for (int r = row0; r < NN; r += rstride) {
        const float4* xr = (const float4*)(x + (size_t)r * FEAT);
        float4 v = xr[lane];
        float wr = ws[r], tr = t[r];
        sx0+=v.x; sx1+=v.y; sx2+=v.z; sx3+=v.w;
        sw0+=wr*v.x; sw1+=wr*v.y; sw2+=wr*v.z; sw3+=wr*v.w;
        st0+=tr*v.x; st1+=tr*v.y; st2+=tr*v.z; st3+=tr*v.w;
        if (lane==0) wsum += wr;
    }
    __shared__ float shx[8][32][4], shw[8][32][4], sht[8][32][4], shwsum[8];
    shx[grp][lane][0]=sx0; shx[grp][lane][1]=sx1; shx[grp][lane][2]=sx2; shx[grp][lane][3]=sx3;
    shw[grp][lane][0]=sw0; shw[grp][lane][1]=sw1; shw[grp][lane][2]=sw2; shw[grp][lane][3]=sw3;
    sht[grp][lane][0]=st0; sht[grp][lane][1]=st1; sht[grp][lane][2]=st2; sht[grp][lane][3]=st3;
    if (lane==0) shwsum[grp]=wsum;
    __syncthreads();
    if (grp==0) {
        float ax[4], aw[4], at[4];
        #pragma unroll
        for (int c=0;c<4;++c){ax[c]=shx[0][lane][c];aw[c]=shw[0][lane][c];at[c]=sht[0][lane][c];}
        #pragma unroll
        for (int g=1;g<8;++g)
            #pragma unroll
            for (int c=0;c<4;++c){ax[c]+=shx[g][lane][c];aw[c]+=shw[g][lane][c];at[c]+=sht[g][lane][c];}
        #pragma unroll
        for (int c=0;c<4;++c){
            atomicAdd(&sums[        4*lane+c], ax[c]);
            atomicAdd(&sums[FEAT  + 4*lane+c], aw[c]);
            atomicAdd(&sums[2*FEAT+ 4*lane+c], at[c]);
        }
        if (lane==0){
            float w=shwsum[0];
            #pragma unroll
            for (int g=1;g<8;++g) w+=shwsum[g];
            atomicAdd(&sums[3*FEAT], w);
        }
    }
}

__global__ __launch_bounds__(128) void k_final(const float* __restrict__ sums,
                                               const float* __restrict__ W1l, const float* __restrict__ W1r,
                                               const float* __restrict__ b1,
                                               const float* __restrict__ W2l, const float* __restrict__ W2r,
                                               const float* __restrict__ b2,
                                               const float* __restrict__ Wout, const float* __restrict__ bout,
                                               float* __restrict__ out) {
    __shared__ float Sx[FEAT], Sw[FEAT], St[FEAT], M1[FEAT], S2[FEAT], G[FEAT];
    __shared__ float Wsum;
    int f = threadIdx.x;
    Sx[f] = sums[f];
    Sw[f] = sums[FEAT + f];
    St[f] = sums[2*FEAT + f];
    if (f == 0) Wsum = sums[3*FEAT];
    __syncthreads();
    float m1 = (float)NN * b1[f];
    float s2 = Wsum * b1[f];
    for (int k = 0; k < FEAT; ++k) {
        float wl = W1l[k*FEAT + f];
        float wr = W1r[k*FEAT + f];
        m1 += Sw[k]*wl + Sx[k]*wr;
        s2 += St[k]*wl + Sw[k]*wr;
    }
    M1[f] = m1; S2[f] = s2;
    __syncthreads();
    float g = 0.f;
    for (int k = 0; k < FEAT; ++k)
        g += S2[k]*W2l[k*FEAT + f] + M1[k]*W2r[k*FEAT + f];
    g = g * (1.0f/(float)NN) + b2[f];
    G[f] = g;
    __syncthreads();
    if (f < NCLS) {
        float o = bout[f];
        for (int k = 0; k < FEAT; ++k)
            o += G[k]*Wout[k*NCLS + f];
        out[f] = o;
    }
}

// ======================= driver =======================

extern "C" void kernel_launch(void* const* d_in, const int* in_sizes, int n_in,
                              void* d_out, int out_size, void* d_ws, size_t ws_size,
                              hipStream_t stream) {
    const float* x    = (const float*)d_in[0];
    const int*   ei   = (const int*)d_in[1];     // [2, NE] flat: src then dst (int32 on device)
    const float* W1l  = (const float*)d_in[2];
    const float* W1r  = (const float*)d_in[3];
    const float* b1   = (const float*)d_in[4];
    const float* W2l  = (const float*)d_in[5];
    const float* W2r  = (const float*)d_in[6];
    const float* b2   = (const float*)d_in[7];
    const float* Wout = (const float*)d_in[8];
    const float* bout = (const float*)d_in[9];
    float* out = (float*)d_out;

    const int4* src4 = (const int4*)ei;
    const int4* dst4 = (const int4*)(ei + NE);

    int dev = 0, coop = 0;
    hipGetDevice(&dev);
    hipDeviceGetAttribute(&coop, hipDeviceAttributeCooperativeLaunch, dev);

    // coop layout: partial[NR*NC*RS] | invc | ws | u | t | fsbuf[385*GRID]
    const size_t need_coop = ((size_t)NR*NC*RS + 4*(size_t)NN + (size_t)(3*FEAT+1)*GRID) * 4;  // ~8.4 MB

    if (coop && ws_size >= need_coop) {
        float* partial = (float*)d_ws;
        float* invc = partial + (size_t)NR*NC*RS;
        float* ws   = invc + NN;
        float* u    = ws + NN;
        float* t    = u + NN;
        float* fsb  = t + NN;

        void* args[] = {
            (void*)&x, (void*)&src4, (void*)&dst4,
            (void*)&W1l, (void*)&W1r, (void*)&b1,
            (void*)&W2l, (void*)&W2r, (void*)&b2,
            (void*)&Wout, (void*)&bout, (void*)&out,
            (void*)&partial, (void*)&invc, (void*)&ws, (void*)&u, (void*)&t, (void*)&fsb
        };
        hipLaunchCooperativeKernel((const void*)k_all, dim3(GRID), dim3(BLK), args, 0, stream);
    } else {
        // device-scope atomic fallback (~2.1 MB ws)
        int*   cnt  = (int*)d_ws;
        float* wsv  = (float*)d_ws + NN;
        float* t    = (float*)d_ws + 2*NN;
        float* sums = (float*)d_ws + 3*NN;
        float* invc = (float*)d_ws + 3*NN + 640;
        float* u    = (float*)d_ws + 3*NN + 640 + NN;

        hipMemsetAsync(d_ws, 0, ((size_t)3*NN + 640) * 4, stream);

        const int EB4 = (NE/4 + 255) / 256;
        const int NB  = (NN + 255) / 256;
        k_count_dev<<<EB4, 256, 0, stream>>>(dst4, cnt);
        k_inv_dev<<<NB, 256, 0, stream>>>(cnt, invc);
        k_ws_dev<<<EB4, 256, 0, stream>>>(src4, dst4, invc, wsv);
        k_u_dev<<<NB, 256, 0, stream>>>(wsv, invc, u);
        k_t_dev<<<EB4, 256, 0, stream>>>(src4, dst4, u, t);
        k_fs_atom<<<256, 256, 0, stream>>>(x, wsv, t, sums);
        k_final<<<1, 128, 0, stream>>>(sums, W1l, W1r, b1, W2l, W2r, b2, Wout, bout, out);
    }
}

// Round 9
// 189.949 us; speedup vs baseline: 2.3525x; 2.3525x over previous
//
#include <hip/hip_runtime.h>

// GraphSAGE (2x SAGEConv mean + global_mean_pool + linear) collapsed algebraically:
// out = (((St@W1l + Sw@W1r + Wsum*b1) @ W2l + (Sw@W1l + Sx@W1r + N*b1) @ W2r)/N + b2) @ Wout + bout
// invc_i = 1/max(indeg_i,1), ws_j = sum_{e:src=j} invc[dst_e], u_j = ws_j*invc_j,
// t_k = sum_{e:src=k} u[dst_e]; Sx/Sw/St = weighted column sums of x; Wsum = sum ws.
//
// R8: back to multi-kernel (R7's cooperative fusion cost ~200 us in grid.sync).
// Count: u16-packed LDS (25 KB), NR=8, grid (32,8)=256.
// Scatter: 64,000 B LDS tables (RS=16000), NR=7, grid (32,7)=224.
// Sibling blocks for a chunk differ by 32 in linear bid (32%8==0) -> same XCD
// under round-robin dispatch -> chunk re-reads stay XCD-L2-local.
// featsums: two-stage dense reduction (no global atomics — they are memory-side
// on gfx950 regardless of scope, proven R2/R4).

#define NN    100000
#define NE    1600000
#define NE4   (NE/4)
#define FEAT  128
#define NCLS  40
#define FSB   2048     // featsums stage-1 blocks

// count pass
#define RSC   12500    // nodes per range (u16-packed: 25,000 B LDS)
#define NRC   8        // ranges
#define NCC   32       // chunks
#define PERC  12500    // int4 per chunk (32*12500 = 400000)

// scatter passes
#define RSV   16000    // nodes per range (64,000 B LDS)
#define NRV   7        // ranges (7*16000 = 112000 >= NN)
#define NCV   32       // chunks
#define PERV  12500    // int4 per chunk

// ======================= count: u16-packed LDS histogram =======================

__global__ __launch_bounds__(1024) void k_cnt(const int4* __restrict__ dst4,
                                              unsigned* __restrict__ pc) {
    __shared__ unsigned tab[RSC / 2];
    const int c = blockIdx.x, r = blockIdx.y;
    for (int j = threadIdx.x; j < RSC / 2; j += 1024) tab[j] = 0u;
    __syncthreads();
    const int base = r * RSC;
    const int i0 = c * PERC;
    for (int i = i0 + (int)threadIdx.x; i < i0 + PERC; i += 1024) {
        int4 d = dst4[i];
        unsigned a;
        a = (unsigned)(d.x - base); if (a < RSC) atomicAdd(&tab[a >> 1], 1u << ((a & 1) * 16));
        a = (unsigned)(d.y - base); if (a < RSC) atomicAdd(&tab[a >> 1], 1u << ((a & 1) * 16));
        a = (unsigned)(d.z - base); if (a < RSC) atomicAdd(&tab[a >> 1], 1u << ((a & 1) * 16));
        a = (unsigned)(d.w - base); if (a < RSC) atomicAdd(&tab[a >> 1], 1u << ((a & 1) * 16));
    }
    __syncthreads();
    unsigned* outp = pc + (size_t)(r * NCC + c) * (RSC / 2);
    for (int j = threadIdx.x; j < RSC / 2; j += 1024) outp[j] = tab[j];
}

__global__ __launch_bounds__(256) void k_merge_invc(const unsigned* __restrict__ pc,
                                                    float* __restrict__ invc) {
    int i = blockIdx.x * 256 + threadIdx.x;
    if (i >= NN) return;
    int rr = i / RSC, jj = i - rr * RSC;
    const unsigned* p = pc + (size_t)rr * NCC * (RSC / 2) + (jj >> 1);
    const unsigned sh = (unsigned)(jj & 1) * 16u;
    unsigned cn = 0;
    #pragma unroll
    for (int c = 0; c < NCC; ++c) cn += (p[(size_t)c * (RSC / 2)] >> sh) & 0xFFFFu;
    invc[i] = 1.0f / (float)(cn > 0u ? cn : 1u);
}

// ======================= scatter: 64 KB LDS tables =======================

// sum val[dst] into table keyed by src (ws pass: val=invc; t pass: val=u)
__global__ __launch_bounds__(1024) void k_scat(const int4* __restrict__ src4,
                                               const int4* __restrict__ dst4,
                                               const float* __restrict__ val,
                                               float* __restrict__ partial) {
    __shared__ float tab[RSV];
    const int c = blockIdx.x, r = blockIdx.y;
    for (int j = threadIdx.x; j < RSV; j += 1024) tab[j] = 0.f;
    __syncthreads();
    const int base = r * RSV;
    const int i0 = c * PERV;
    for (int i = i0 + (int)threadIdx.x; i < i0 + PERV; i += 1024) {
        int4 s = src4[i];
        int4 d = dst4[i];
        unsigned a;
        a = (unsigned)(s.x - base); if (a < RSV) atomicAdd(&tab[a], val[d.x]);
        a = (unsigned)(s.y - base); if (a < RSV) atomicAdd(&tab[a], val[d.y]);
        a = (unsigned)(s.z - base); if (a < RSV) atomicAdd(&tab[a], val[d.z]);
        a = (unsigned)(s.w - base); if (a < RSV) atomicAdd(&tab[a], val[d.w]);
    }
    __syncthreads();
    float* outp = partial + (size_t)(r * NCV + c) * RSV;
    for (int j = threadIdx.x; j < RSV; j += 1024) outp[j] = tab[j];
}

__global__ __launch_bounds__(256) void k_merge_ws(const float* __restrict__ partial,
                                                  const float* __restrict__ invc,
                                                  float* __restrict__ ws, float* __restrict__ u) {
    int i = blockIdx.x * 256 + threadIdx.x;
    if (i >= NN) return;
    int rr = i / RSV, jj = i - rr * RSV;
    const float* p = partial + (size_t)rr * NCV * RSV + jj;
    float w = 0.f;
    #pragma unroll
    for (int c = 0; c < NCV; ++c) w += p[(size_t)c * RSV];
    ws[i] = w;
    u[i] = w * invc[i];
}

__global__ __launch_bounds__(256) void k_merge_t(const float* __restrict__ partial,
                                                 float* __restrict__ t) {
    int i = blockIdx.x * 256 + threadIdx.x;
    if (i >= NN) return;
    int rr = i / RSV, jj = i - rr * RSV;
    const float* p = partial + (size_t)rr * NCV * RSV + jj;
    float v = 0.f;
    #pragma unroll
    for (int c = 0; c < NCV; ++c) v += p[(size_t)c * RSV];
    t[i] = v;
}

// ======================= featsums: two-stage, no atomics =======================

__global__ __launch_bounds__(256) void k_fs1(const float* __restrict__ x,
                                             const float* __restrict__ ws,
                                             const float* __restrict__ t,
                                             float* __restrict__ p1) {
    int lane = threadIdx.x & 31;
    int grp  = threadIdx.x >> 5;          // 0..7
    int row0 = blockIdx.x * 8 + grp;
    const int rstride = FSB * 8;

    float sx0=0,sx1=0,sx2=0,sx3=0;
    float sw0=0,sw1=0,sw2=0,sw3=0;
    float st0=0,st1=0,st2=0,st3=0;
    float wsum = 0.f;

    for (int r = row0; r < NN; r += rstride) {
        const float4* xr = (const float4*)(x + (size_t)r * FEAT);
        float4 v = xr[lane];
        float wr = ws[r];
        float tr = t[r];
        sx0 += v.x; sx1 += v.y; sx2 += v.z; sx3 += v.w;
        sw0 += wr*v.x; sw1 += wr*v.y; sw2 += wr*v.z; sw3 += wr*v.w;
        st0 += tr*v.x; st1 += tr*v.y; st2 += tr*v.z; st3 += tr*v.w;
        if (lane == 0) wsum += wr;
    }

    __shared__ float shx[8][32][4];
    __shared__ float shw[8][32][4];
    __shared__ float sht[8][32][4];
    __shared__ float shwsum[8];
    shx[grp][lane][0]=sx0; shx[grp][lane][1]=sx1; shx[grp][lane][2]=sx2; shx[grp][lane][3]=sx3;
    shw[grp][lane][0]=sw0; shw[grp][lane][1]=sw1; shw[grp][lane][2]=sw2; shw[grp][lane][3]=sw3;
    sht[grp][lane][0]=st0; sht[grp][lane][1]=st1; sht[grp][lane][2]=st2; sht[grp][lane][3]=st3;
    if (lane == 0) shwsum[grp] = wsum;
    __syncthreads();

    if (grp == 0) {
        const int b = blockIdx.x;
        float ax[4], aw[4], at[4];
        #pragma unroll
        for (int c = 0; c < 4; ++c) { ax[c]=shx[0][lane][c]; aw[c]=shw[0][lane][c]; at[c]=sht[0][lane][c]; }
        #pragma unroll
        for (int g = 1; g < 8; ++g) {
            #pragma unroll
            for (int c = 0; c < 4; ++c) {
                ax[c]+=shx[g][lane][c]; aw[c]+=shw[g][lane][c]; at[c]+=sht[g][lane][c];
            }
        }
        #pragma unroll
        for (int c = 0; c < 4; ++c) {
            p1[(size_t)(        4*lane + c) * FSB + b] = ax[c];
            p1[(size_t)(FEAT  + 4*lane + c) * FSB + b] = aw[c];
            p1[(size_t)(2*FEAT+ 4*lane + c) * FSB + b] = at[c];
        }
        if (lane == 0) {
            float w = shwsum[0];
            #pragma unroll
            for (int g = 1; g < 8; ++g) w += shwsum[g];
            p1[(size_t)(3*FEAT) * FSB + b] = w;
        }
    }
}

__global__ __launch_bounds__(256) void k_fs2(const float* __restrict__ p1, float* __restrict__ sums) {
    const int v = blockIdx.x;
    float s = 0.f;
    for (int b = threadIdx.x; b < FSB; b += 256) s += p1[(size_t)v * FSB + b];
    __shared__ float sh[256];
    sh[threadIdx.x] = s;
    __syncthreads();
    for (int off = 128; off > 0; off >>= 1) {
        if (threadIdx.x < off) sh[threadIdx.x] += sh[threadIdx.x + off];
        __syncthreads();
    }
    if (threadIdx.x == 0) sums[v] = sh[0];
}

// ======================= final matvecs =======================

__global__ __launch_bounds__(128) void k_final(const float* __restrict__ sums,
                                               const float* __restrict__ W1l, const float* __restrict__ W1r,
                                               const float* __restrict__ b1,
                                               const float* __restrict__ W2l, const float* __restrict__ W2r,
                                               const float* __restrict__ b2,
                                               const float* __restrict__ Wout, const float* __restrict__ bout,
                                               float* __restrict__ out) {
    __shared__ float Sx[FEAT], Sw[FEAT], St[FEAT], M1[FEAT], S2[FEAT], G[FEAT];
    __shared__ float Wsum;
    int f = threadIdx.x;
    Sx[f] = sums[f];
    Sw[f] = sums[FEAT + f];
    St[f] = sums[2*FEAT + f];
    if (f == 0) Wsum = sums[3*FEAT];
    __syncthreads();

    float m1 = (float)NN * b1[f];
    float s2 = Wsum * b1[f];
    for (int k = 0; k < FEAT; ++k) {
        float wl = W1l[k*FEAT + f];
        float wr = W1r[k*FEAT + f];
        m1 += Sw[k]*wl + Sx[k]*wr;
        s2 += St[k]*wl + Sw[k]*wr;
    }
    M1[f] = m1; S2[f] = s2;
    __syncthreads();

    float g = 0.f;
    for (int k = 0; k < FEAT; ++k)
        g += S2[k]*W2l[k*FEAT + f] + M1[k]*W2r[k*FEAT + f];
    g = g * (1.0f/(float)NN) + b2[f];
    G[f] = g;
    __syncthreads();

    if (f < NCLS) {
        float o = bout[f];
        for (int k = 0; k < FEAT; ++k)
            o += G[k]*Wout[k*NCLS + f];
        out[f] = o;
    }
}

// ======================= device-scope fallback (tiny ws_size) =======================

__global__ __launch_bounds__(256) void k_count_dev(const int4* __restrict__ dst4, int* __restrict__ cnt) {
    int i = blockIdx.x * 256 + threadIdx.x;
    if (i >= NE4) return;
    int4 d = dst4[i];
    atomicAdd(&cnt[d.x], 1); atomicAdd(&cnt[d.y], 1);
    atomicAdd(&cnt[d.z], 1); atomicAdd(&cnt[d.w], 1);
}

__global__ __launch_bounds__(256) void k_inv_dev(const int* __restrict__ cnt, float* __restrict__ invc) {
    int i = blockIdx.x * 256 + threadIdx.x;
    if (i >= NN) return;
    int c = cnt[i];
    invc[i] = 1.0f / (float)(c > 0 ? c : 1);
}

__global__ __launch_bounds__(256) void k_ws_dev(const int4* __restrict__ src4, const int4* __restrict__ dst4,
                                                const float* __restrict__ invc, float* __restrict__ ws) {
    int i = blockIdx.x * 256 + threadIdx.x;
    if (i >= NE4) return;
    int4 s = src4[i];
    int4 d = dst4[i];
    atomicAdd(&ws[s.x], invc[d.x]); atomicAdd(&ws[s.y], invc[d.y]);
    atomicAdd(&ws[s.z], invc[d.z]); atomicAdd(&ws[s.w], invc[d.w]);
}

__global__ __launch_bounds__(256) void k_u_dev(const float* __restrict__ ws, const float* __restrict__ invc,
                                               float* __restrict__ u) {
    int i = blockIdx.x * 256 + threadIdx.x;
    if (i >= NN) return;
    u[i] = ws[i] * invc[i];
}

__global__ __launch_bounds__(256) void k_t_dev(const int4* __restrict__ src4, const int4* __restrict__ dst4,
                                               const float* __restrict__ u, float* __restrict__ t) {
    int i = blockIdx.x * 256 + threadIdx.x;
    if (i >= NE4) return;
    int4 s = src4[i];
    int4 d = dst4[i];
    atomicAdd(&t[s.x], u[d.x]); atomicAdd(&t[s.y], u[d.y]);
    atomicAdd(&t[s.z], u[d.z]); atomicAdd(&t[s.w], u[d.w]);
}

__global__ __launch_bounds__(256) void k_fs_atom(const float* __restrict__ x,
                                                 const float* __restrict__ ws,
                                                 const float* __restrict__ t,
                                                 float* __restrict__ sums) {
    int lane = threadIdx.x & 31;
    int grp  = threadIdx.x >> 5;
    int row0 = blockIdx.x * 8 + grp;
    int rstride = gridDim.x * 8;
    float sx0=0,sx1=0,sx2=0,sx3=0, sw0=0,sw1=0,sw2=0,sw3=0, st0=0,st1=0,st2=0,st3=0, wsum=0.f;
    for (int r = row0; r < NN; r += rstride) {
        const float4* xr = (const float4*)(x + (size_t)r * FEAT);
        float4 v = xr[lane];
        float wr = ws[r], tr = t[r];
        sx0+=v.x; sx1+=v.y; sx2+=v.z; sx3+=v.w;
        sw0+=wr*v.x; sw1+=wr*v.y; sw2+=wr*v.z; sw3+=wr*v.w;
        st0+=tr*v.x; st1+=tr*v.y; st2+=tr*v.z; st3+=tr*v.w;
        if (lane==0) wsum += wr;
    }
    __shared__ float shx[8][32][4], shw[8][32][4], sht[8][32][4], shwsum[8];
    shx[grp][lane][0]=sx0; shx[grp][lane][1]=sx1; shx[grp][lane][2]=sx2; shx[grp][lane][3]=sx3;
    shw[grp][lane][0]=sw0; shw[grp][lane][1]=sw1; shw[grp][lane][2]=sw2; shw[grp][lane][3]=sw3;
    sht[grp][lane][0]=st0; sht[grp][lane][1]=st1; sht[grp][lane][2]=st2; sht[grp][lane][3]=st3;
    if (lane==0) shwsum[grp]=wsum;
    __syncthreads();
    if (grp==0) {
        float ax[4], aw[4], at[4];
        #pragma unroll
        for (int c=0;c<4;++c){ax[c]=shx[0][lane][c];aw[c]=shw[0][lane][c];at[c]=sht[0][lane][c];}
        #pragma unroll
        for (int g=1;g<8;++g)
            #pragma unroll
            for (int c=0;c<4;++c){ax[c]+=shx[g][lane][c];aw[c]+=shw[g][lane][c];at[c]+=sht[g][lane][c];}
        #pragma unroll
        for (int c=0;c<4;++c){
            atomicAdd(&sums[        4*lane+c], ax[c]);
            atomicAdd(&sums[FEAT  + 4*lane+c], aw[c]);
            atomicAdd(&sums[2*FEAT+ 4*lane+c], at[c]);
        }
        if (lane==0){
            float w=shwsum[0];
            #pragma unroll
            for (int g=1;g<8;++g) w+=shwsum[g];
            atomicAdd(&sums[3*FEAT], w);
        }
    }
}

// ======================= driver =======================

extern "C" void kernel_launch(void* const* d_in, const int* in_sizes, int n_in,
                              void* d_out, int out_size, void* d_ws, size_t ws_size,
                              hipStream_t stream) {
    const float* x    = (const float*)d_in[0];
    const int*   ei   = (const int*)d_in[1];     // [2, NE] flat: src then dst (int32 on device)
    const float* W1l  = (const float*)d_in[2];
    const float* W1r  = (const float*)d_in[3];
    const float* b1   = (const float*)d_in[4];
    const float* W2l  = (const float*)d_in[5];
    const float* W2r  = (const float*)d_in[6];
    const float* b2   = (const float*)d_in[7];
    const float* Wout = (const float*)d_in[8];
    const float* bout = (const float*)d_in[9];
    float* out = (float*)d_out;

    const int4* src4 = (const int4*)ei;
    const int4* dst4 = (const int4*)(ei + NE);

    // partial region holds (max of): scat partial 7*32*16000 = 3.584M floats,
    // count partial 8*32*6250 = 1.6M u32, fs1 p1 385*2048 = 0.788M floats.
    const size_t PART = (size_t)NRV * NCV * RSV;           // 3,584,000 floats
    const size_t need = (PART + (size_t)4*NN + 640) * 4;   // ~15.9 MB

    if (ws_size >= need) {
        float* partial = (float*)d_ws;
        float* invc = partial + PART;
        float* ws   = invc + NN;
        float* u    = ws + NN;
        float* t    = u + NN;
        float* sums = t + NN;          // 640 floats

        const int NB = (NN + 255) / 256;

        k_cnt<<<dim3(NCC, NRC), 1024, 0, stream>>>(dst4, (unsigned*)partial);
        k_merge_invc<<<NB, 256, 0, stream>>>((const unsigned*)partial, invc);
        k_scat<<<dim3(NCV, NRV), 1024, 0, stream>>>(src4, dst4, invc, partial);
        k_merge_ws<<<NB, 256, 0, stream>>>(partial, invc, ws, u);
        k_scat<<<dim3(NCV, NRV), 1024, 0, stream>>>(src4, dst4, u, partial);
        k_merge_t<<<NB, 256, 0, stream>>>(partial, t);
        k_fs1<<<FSB, 256, 0, stream>>>(x, ws, t, partial);   // p1 aliases partial
        k_fs2<<<385, 256, 0, stream>>>(partial, sums);
        k_final<<<1, 128, 0, stream>>>(sums, W1l, W1r, b1, W2l, W2r, b2, Wout, bout, out);
    } else {
        // device-scope atomic fallback (~2.1 MB ws)
        int*   cnt  = (int*)d_ws;
        float* wsv  = (float*)d_ws + NN;
        float* t    = (float*)d_ws + 2*NN;
        float* sums = (float*)d_ws + 3*NN;
        float* invc = (float*)d_ws + 3*NN + 640;
        float* u    = (float*)d_ws + 3*NN + 640 + NN;

        hipMemsetAsync(d_ws, 0, ((size_t)3*NN + 640) * 4, stream);

        const int EB4 = (NE4 + 255) / 256;
        const int NB  = (NN + 255) / 256;
        k_count_dev<<<EB4, 256, 0, stream>>>(dst4, cnt);
        k_inv_dev<<<NB, 256, 0, stream>>>(cnt, invc);
        k_ws_dev<<<EB4, 256, 0, stream>>>(src4, dst4, invc, wsv);
        k_u_dev<<<NB, 256, 0, stream>>>(wsv, invc, u);
        k_t_dev<<<EB4, 256, 0, stream>>>(src4, dst4, u, t);
        k_fs_atom<<<256, 256, 0, stream>>>(x, wsv, t, sums);
        k_final<<<1, 128, 0, stream>>>(sums, W1l, W1r, b1, W2l, W2r, b2, Wout, bout, out);
    }
}